// Round 8
// baseline (111.809 us; speedup 1.0000x reference)
//
#include <hip/hip_runtime.h>

namespace {

constexpr int NB = 4, L = 4096, HC = 4, D = 1024, KW = 4;
constexpr int PAD = 6;                 // (KW-1)*DIL
constexpr float EPS = 1e-5f;
constexpr int ST = 4;                  // rows per step
constexpr int NSTEP = 16;              // steps per block
constexpr int CL = ST * NSTEP;         // 64 rows per block
constexpr int NT = L / CL;             // 64
constexpr int BDIM = 256;              // 4 waves

typedef float f32x4 __attribute__((ext_vector_type(4)));

#define LGKM_BARRIER() do {                                    \
    asm volatile("s_waitcnt lgkmcnt(0)" ::: "memory");         \
    __builtin_amdgcn_s_barrier();                              \
} while (0)

__device__ __forceinline__ void stage16(const float* g, float* l) {
    __builtin_amdgcn_global_load_lds(
        (const __attribute__((address_space(1))) void*)g,
        (__attribute__((address_space(3))) void*)l, 16, 0, 0);
}

__global__ __launch_bounds__(BDIM, 4) void engram_shortconv_tri(
    const float* __restrict__ x,
    const float* __restrict__ nw,
    const float* __restrict__ cw,
    float* __restrict__ out)
{
    __shared__ float s_buf[3][ST][D];   // 48 KiB staged x (triple buffer)
    __shared__ float s_inv[2][ST];
    __shared__ float s_invh[PAD];

    // Bijective XCD-chunked swizzle (1024 blocks, 8 XCDs): halo-sharing
    // neighbor blocks land on the same XCD's L2.
    const int lblk = (blockIdx.x & 7) * 128 + (blockIdx.x >> 3);
    const int t    = lblk % NT;
    const int hc   = (lblk / NT) % HC;
    const int b    = lblk / (NT * HC);
    const int l0   = t * CL;

    const int tid  = threadIdx.x;
    const int wave = tid >> 6;
    const int lane = tid & 63;

    const size_t rs = (size_t)HC * D;
    const float* xbase = x + ((size_t)b * L * HC + (size_t)hc) * D;
    const float* xcol  = xbase + tid * 4;
    float*       ocol  = out + ((size_t)b * L * HC + (size_t)hc) * D + tid * 4;

    // ---- 1. async stage of steps 0..2 ----
    #pragma unroll
    for (int s = 0; s < 3; ++s)
        #pragma unroll
        for (int r = 0; r < ST; ++r)
            stage16(xcol + (size_t)(l0 + s * ST + r) * rs, &s_buf[s][r][wave * 256]);

    // ---- 2. weights ----
    const float4 nw4 = *(const float4*)(nw + (size_t)hc * D + tid * 4);
    float4 cwv[4];
    #pragma unroll
    for (int j = 0; j < 4; ++j)
        cwv[j] = *(const float4*)(cw + ((size_t)hc * D + tid * 4 + j) * KW);

    // ---- 3. per-thread halo slice (raw) ----
    float win[PAD][4];
    #pragma unroll
    for (int r = 0; r < PAD; ++r) {
        const int l = l0 - PAD + r;
        float4 v = make_float4(0.f, 0.f, 0.f, 0.f);
        if (l >= 0) v = *(const float4*)(xcol + (size_t)l * rs);
        win[r][0] = v.x; win[r][1] = v.y; win[r][2] = v.z; win[r][3] = v.w;
    }

    // ---- 4. wave-per-row halo RMS ----
    #pragma unroll
    for (int rr = wave; rr < PAD; rr += 4) {
        const int l = l0 - PAD + rr;
        float ss = 0.0f;
        if (l >= 0) {
            const float* rp = xbase + (size_t)l * rs;
            #pragma unroll
            for (int q = 0; q < 4; ++q) {
                const f32x4 v = *(const f32x4*)(rp + lane * 4 + q * 256);
                ss = fmaf(v.x, v.x, fmaf(v.y, v.y, fmaf(v.z, v.z, fmaf(v.w, v.w, ss))));
            }
        }
        #pragma unroll
        for (int off = 32; off >= 1; off >>= 1) ss += __shfl_xor(ss, off);
        if (lane == 0) s_invh[rr] = rsqrtf(ss * (1.0f / D) + EPS);
    }

    // ---- 5. fold norm gain into conv taps ----
    float wk[4][4];
    {
        const float gv[4] = { nw4.x, nw4.y, nw4.z, nw4.w };
        #pragma unroll
        for (int j = 0; j < 4; ++j) {
            wk[j][0] = cwv[j].x * gv[j]; wk[j][1] = cwv[j].y * gv[j];
            wk[j][2] = cwv[j].z * gv[j]; wk[j][3] = cwv[j].w * gv[j];
        }
    }

    // ---- 6. barriers + halo scale + seed s_inv[0] ----
    LGKM_BARRIER();                                     // s_invh visible
    #pragma unroll
    for (int r = 0; r < PAD; ++r) {
        const float iv = s_invh[r];
        win[r][0] *= iv; win[r][1] *= iv; win[r][2] *= iv; win[r][3] *= iv;
    }
    asm volatile("s_waitcnt vmcnt(0)" ::: "memory");    // my stages landed
    __builtin_amdgcn_s_barrier();                       // everyone's landed
    {
        const int row = wave;
        float ss = 0.0f;
        #pragma unroll
        for (int q = 0; q < 4; ++q) {
            const f32x4 v = *(const f32x4*)&s_buf[0][row][lane * 4 + q * 256];
            ss = fmaf(v.x, v.x, fmaf(v.y, v.y, fmaf(v.z, v.z, fmaf(v.w, v.w, ss))));
        }
        #pragma unroll
        for (int off = 32; off >= 1; off >>= 1) ss += __shfl_xor(ss, off);
        if (lane == 0) s_inv[0][row] = rsqrtf(ss * (1.0f / D) + EPS);
    }
    LGKM_BARRIER();                                     // s_inv[0] visible

    // ---- steady-state: 1 barrier per step ----
    #pragma unroll
    for (int s = 0; s < NSTEP; ++s) {
        // (a) reduce next buffer -> s_inv[(s+1)&1] (overlaps conv below)
        if (s < NSTEP - 1) {
            const int row = wave;
            const float* rp = &s_buf[(s + 1) % 3][row][0];
            float ss = 0.0f;
            #pragma unroll
            for (int q = 0; q < 4; ++q) {
                const f32x4 v = *(const f32x4*)(rp + lane * 4 + q * 256);
                ss = fmaf(v.x, v.x, fmaf(v.y, v.y, fmaf(v.z, v.z, fmaf(v.w, v.w, ss))));
            }
            #pragma unroll
            for (int off = 32; off >= 1; off >>= 1) ss += __shfl_xor(ss, off);
            if (lane == 0) s_inv[(s + 1) & 1][row] = rsqrtf(ss * (1.0f / D) + EPS);
        }

        // (b) conv step s from own-quarter LDS (no waits on this path)
        const int base = l0 + s * ST;
        float cur[ST][4];
        #pragma unroll
        for (int r = 0; r < ST; ++r) {
            const f32x4 v = *(const f32x4*)&s_buf[s % 3][r][tid * 4];
            const float iv = s_inv[s & 1][r];
            cur[r][0] = v.x * iv; cur[r][1] = v.y * iv;
            cur[r][2] = v.z * iv; cur[r][3] = v.w * iv;
        }
        #pragma unroll
        for (int i = 0; i < ST; ++i) {
            float av[4];
            #pragma unroll
            for (int j = 0; j < 4; ++j) {
                float a = 0.0f;
                #pragma unroll
                for (int k = 0; k < 4; ++k) {
                    const int rel = i - 6 + 2 * k;
                    const float xv = (rel < 0) ? win[6 + rel][j] : cur[rel][j];
                    a = fmaf(wk[j][k], xv, a);
                }
                av[j] = a / (1.0f + __expf(-a));
            }
            f32x4 o = { av[0], av[1], av[2], av[3] };
            *(f32x4*)(ocol + (size_t)(base + i) * rs) = o;
        }

        // (c) rotate halo: keep last 2, append 4 scaled rows
        win[0][0]=win[4][0]; win[0][1]=win[4][1]; win[0][2]=win[4][2]; win[0][3]=win[4][3];
        win[1][0]=win[5][0]; win[1][1]=win[5][1]; win[1][2]=win[5][2]; win[1][3]=win[5][3];
        #pragma unroll
        for (int r = 0; r < ST; ++r) {
            win[2 + r][0] = cur[r][0]; win[2 + r][1] = cur[r][1];
            win[2 + r][2] = cur[r][2]; win[2 + r][3] = cur[r][3];
        }

        // (d) stage step s+3 into the buffer just consumed
        if (s < NSTEP - 3) {
            asm volatile("s_waitcnt lgkmcnt(0)" ::: "memory");
            __builtin_amdgcn_sched_barrier(0);
            #pragma unroll
            for (int r = 0; r < ST; ++r)
                stage16(xcol + (size_t)(l0 + (s + 3) * ST + r) * rs,
                        &s_buf[s % 3][r][wave * 256]);
            __builtin_amdgcn_sched_barrier(0);
        }

        // (e) counted vmcnt (stage(s+2) landed block-wide after barrier)
        if (s <= NSTEP - 4)      asm volatile("s_waitcnt vmcnt(8)" ::: "memory");
        else if (s == NSTEP - 3) asm volatile("s_waitcnt vmcnt(4)" ::: "memory");
        if (s < NSTEP - 1) LGKM_BARRIER();
    }
}

} // namespace

extern "C" void kernel_launch(void* const* d_in, const int* in_sizes, int n_in,
                              void* d_out, int out_size, void* d_ws, size_t ws_size,
                              hipStream_t stream) {
    const float* x  = (const float*)d_in[0];   // [B, L, HC, D] f32
    const float* nw = (const float*)d_in[1];   // [HC, D] f32
    const float* cw = (const float*)d_in[2];   // [C, 1, K] f32
    float* out = (float*)d_out;                // [B, L, HC, D] f32

    const int nblocks = NB * HC * NT;          // 1024
    engram_shortconv_tri<<<dim3(nblocks), dim3(BDIM), 0, stream>>>(x, nw, cw, out);
}

// Round 9
// 96.846 us; speedup vs baseline: 1.1545x; 1.1545x over previous
//
#include <hip/hip_runtime.h>

namespace {

constexpr int NB = 4, L = 4096, HC = 4, D = 1024, KW = 4;
constexpr int PAD = 6;                 // (KW-1)*DIL
constexpr float EPS = 1e-5f;
constexpr int ST = 2;                  // rows per step
constexpr int NSTEP = 32;              // steps per block
constexpr int CL = ST * NSTEP;         // 64 rows per block
constexpr int NT = L / CL;             // 64
constexpr int BDIM = 256;              // 4 waves

typedef float f32x4 __attribute__((ext_vector_type(4)));

#define LGKM_BARRIER() do {                                    \
    asm volatile("s_waitcnt lgkmcnt(0)" ::: "memory");         \
    __builtin_amdgcn_s_barrier();                              \
} while (0)

__device__ __forceinline__ void stage16(const float* g, float* l) {
    __builtin_amdgcn_global_load_lds(
        (const __attribute__((address_space(1))) void*)g,
        (__attribute__((address_space(3))) void*)l, 16, 0, 0);
}

__global__ __launch_bounds__(BDIM, 4) void engram_shortconv_v9(
    const float* __restrict__ x,
    const float* __restrict__ nw,
    const float* __restrict__ cw,
    float* __restrict__ out)
{
    __shared__ float s_buf[3][ST][D];      // 24 KiB triple-buffered x
    __shared__ float s_part[PAD][BDIM];    // 6 KiB halo partials
    __shared__ float s_inv2[2][ST];
    __shared__ float s_invh[PAD];

    // Bijective XCD-chunked swizzle (1024 blocks, 8 XCDs).
    const int lblk = (blockIdx.x & 7) * 128 + (blockIdx.x >> 3);
    const int t    = lblk % NT;
    const int hc   = (lblk / NT) % HC;
    const int b    = lblk / (NT * HC);
    const int l0   = t * CL;

    const int tid  = threadIdx.x;
    const int wave = tid >> 6;
    const int lane = tid & 63;

    const size_t rs = (size_t)HC * D;
    const float* xcol = x   + ((size_t)b * L * HC + (size_t)hc) * D + tid * 4;
    float*       ocol = out + ((size_t)b * L * HC + (size_t)hc) * D + tid * 4;

    // ---- issue order matters for vmcnt counting: weights(5), halo(6), stages(6) ----
    const float4 nw4 = *(const float4*)(nw + (size_t)hc * D + tid * 4);
    float4 cwv[4];
    #pragma unroll
    for (int j = 0; j < 4; ++j)
        cwv[j] = *(const float4*)(cw + ((size_t)hc * D + tid * 4 + j) * KW);

    float win[PAD][4];   // halo rows l0-6 .. l0-1
    #pragma unroll
    for (int r = 0; r < PAD; ++r) {
        const int l = l0 - PAD + r;
        float4 v = make_float4(0.f, 0.f, 0.f, 0.f);
        if (l >= 0) v = *(const float4*)(xcol + (size_t)l * rs);
        win[r][0] = v.x; win[r][1] = v.y; win[r][2] = v.z; win[r][3] = v.w;
    }

    #pragma unroll
    for (int s = 0; s < 3; ++s)
        #pragma unroll
        for (int r = 0; r < ST; ++r)
            stage16(xcol + (size_t)(l0 + s * ST + r) * rs, &s_buf[s][r][wave * 256]);

    // fold norm gain into conv taps
    float wk[4][4];
    {
        const float gv[4] = { nw4.x, nw4.y, nw4.z, nw4.w };
        #pragma unroll
        for (int j = 0; j < 4; ++j) {
            wk[j][0] = cwv[j].x * gv[j]; wk[j][1] = cwv[j].y * gv[j];
            wk[j][2] = cwv[j].z * gv[j]; wk[j][3] = cwv[j].w * gv[j];
        }
    }

    // ---- halo RMS from per-thread regs (single read of halo) ----
    #pragma unroll
    for (int r = 0; r < PAD; ++r)
        s_part[r][tid] = win[r][0]*win[r][0] + win[r][1]*win[r][1]
                       + win[r][2]*win[r][2] + win[r][3]*win[r][3];
    LGKM_BARRIER();
    {
        int rr = wave;
        float s1 = s_part[rr][lane]       + s_part[rr][lane + 64]
                 + s_part[rr][lane + 128] + s_part[rr][lane + 192];
        #pragma unroll
        for (int off = 32; off >= 1; off >>= 1) s1 += __shfl_xor(s1, off);
        if (lane == 0) s_invh[rr] = rsqrtf(s1 * (1.0f / D) + EPS);
        rr = wave + 4;
        if (rr < PAD) {
            float s2 = s_part[rr][lane]       + s_part[rr][lane + 64]
                     + s_part[rr][lane + 128] + s_part[rr][lane + 192];
            #pragma unroll
            for (int off = 32; off >= 1; off >>= 1) s2 += __shfl_xor(s2, off);
            if (lane == 0) s_invh[rr] = rsqrtf(s2 * (1.0f / D) + EPS);
        }
    }
    LGKM_BARRIER();
    #pragma unroll
    for (int r = 0; r < PAD; ++r) {
        const float iv = s_invh[r];
        win[r][0] *= iv; win[r][1] *= iv; win[r][2] *= iv; win[r][3] *= iv;
    }

    // stages 0,1 retired (stage(2) may fly); cross-wave visible after barrier
    asm volatile("s_waitcnt vmcnt(2)" ::: "memory");
    __builtin_amdgcn_s_barrier();
    {   // seed s_inv2[0][0..1] from buf0 (waves 0,2 -> row0; 1,3 -> row1)
        const int row = wave & 1;
        const float* rp = &s_buf[0][row][0];
        float ss = 0.0f;
        #pragma unroll
        for (int q = 0; q < 4; ++q) {
            const f32x4 v = *(const f32x4*)(rp + lane * 4 + q * 256);
            ss = fmaf(v.x, v.x, fmaf(v.y, v.y, fmaf(v.z, v.z, fmaf(v.w, v.w, ss))));
        }
        #pragma unroll
        for (int off = 32; off >= 1; off >>= 1) ss += __shfl_xor(ss, off);
        if (lane == 0) s_inv2[0][row] = rsqrtf(ss * (1.0f / D) + EPS);
    }
    LGKM_BARRIER();

    float* p0 = &s_buf[0][0][0];
    float* p1 = &s_buf[1][0][0];
    float* p2 = &s_buf[2][0][0];

    #pragma unroll 1
    for (int s = 0; s < NSTEP; ++s) {
        // (a) reduce-ahead: rows of p1 (= stage(s+1) data) -> s_inv2[(s+1)&1]
        if (s < NSTEP - 1) {
            const int row = wave & 1;
            const float* rp = p1 + row * D;
            float ss = 0.0f;
            #pragma unroll
            for (int q = 0; q < 4; ++q) {
                const f32x4 v = *(const f32x4*)(rp + lane * 4 + q * 256);
                ss = fmaf(v.x, v.x, fmaf(v.y, v.y, fmaf(v.z, v.z, fmaf(v.w, v.w, ss))));
            }
            #pragma unroll
            for (int off = 32; off >= 1; off >>= 1) ss += __shfl_xor(ss, off);
            if (lane == 0) s_inv2[(s + 1) & 1][row] = rsqrtf(ss * (1.0f / D) + EPS);
        }

        // (b) conv math for this step's ST rows (own-quarter LDS reads only)
        const int base = l0 + s * ST;
        float cur[ST][4];
        #pragma unroll
        for (int r = 0; r < ST; ++r) {
            const f32x4 v = *(const f32x4*)(p0 + r * D + tid * 4);
            const float iv = s_inv2[s & 1][r];
            cur[r][0] = v.x * iv; cur[r][1] = v.y * iv;
            cur[r][2] = v.z * iv; cur[r][3] = v.w * iv;
        }
        float ov[ST][4];
        #pragma unroll
        for (int i = 0; i < ST; ++i) {
            #pragma unroll
            for (int j = 0; j < 4; ++j) {
                float a = 0.0f;
                #pragma unroll
                for (int k = 0; k < 4; ++k) {
                    const int rel = i - 6 + 2 * k;
                    const float xv = (rel < 0) ? win[6 + rel][j] : cur[rel][j];
                    a = fmaf(wk[j][k], xv, a);
                }
                ov[i][j] = a / (1.0f + __expf(-a));
            }
        }

        // (c) rotate halo (scaled)
        #pragma unroll
        for (int r = 0; r < PAD - ST; ++r) {
            win[r][0] = win[r + ST][0]; win[r][1] = win[r + ST][1];
            win[r][2] = win[r + ST][2]; win[r][3] = win[r + ST][3];
        }
        #pragma unroll
        for (int r = 0; r < ST; ++r) {
            win[PAD - ST + r][0] = cur[r][0]; win[PAD - ST + r][1] = cur[r][1];
            win[PAD - ST + r][2] = cur[r][2]; win[PAD - ST + r][3] = cur[r][3];
        }

        // (d) stage(s+3) into p0 (just consumed) — issued BEFORE the stores
        if (s < NSTEP - 3) {
            asm volatile("s_waitcnt lgkmcnt(0)" ::: "memory");
            __builtin_amdgcn_sched_barrier(0);
            #pragma unroll
            for (int r = 0; r < ST; ++r)
                stage16(xcol + (size_t)(l0 + (s + 3) * ST + r) * rs,
                        p0 + r * D + wave * 256);
            __builtin_amdgcn_sched_barrier(0);
        }

        // stores (nontemporal: output is never re-read, keep L2 for x)
        #pragma unroll
        for (int i = 0; i < ST; ++i) {
            f32x4 o = { ov[i][0], ov[i][1], ov[i][2], ov[i][3] };
            __builtin_nontemporal_store(o, (f32x4*)(ocol + (size_t)(base + i) * rs));
        }

        // (e) counted vmcnt: guarantee stage(s+2) retired; newer ops stay in flight
        if (s < NSTEP - 1) {
            if (s <= NSTEP - 4)      asm volatile("s_waitcnt vmcnt(6)" ::: "memory");
            else if (s == NSTEP - 3) asm volatile("s_waitcnt vmcnt(4)" ::: "memory");
            LGKM_BARRIER();
        }

        float* tmp = p0; p0 = p1; p1 = p2; p2 = tmp;
    }
}

} // namespace

extern "C" void kernel_launch(void* const* d_in, const int* in_sizes, int n_in,
                              void* d_out, int out_size, void* d_ws, size_t ws_size,
                              hipStream_t stream) {
    const float* x  = (const float*)d_in[0];   // [B, L, HC, D] f32
    const float* nw = (const float*)d_in[1];   // [HC, D] f32
    const float* cw = (const float*)d_in[2];   // [C, 1, K] f32
    float* out = (float*)d_out;                // [B, L, HC, D] f32

    const int nblocks = NB * HC * NT;          // 1024
    engram_shortconv_v9<<<dim3(nblocks), dim3(BDIM), 0, stream>>>(x, nw, cw, out);
}